// Round 3
// baseline (155.371 us; speedup 1.0000x reference)
//
#include <hip/hip_runtime.h>
#include <cfloat>
#include <cmath>

#define DIM 64
#define TT 2048
#define NTOT 65536
#define KE 1024

typedef _Float16 f16x8 __attribute__((ext_vector_type(8)));
typedef _Float16 f16x4 __attribute__((ext_vector_type(4)));
typedef float    f32x4 __attribute__((ext_vector_type(4)));

// ws layout (bytes):
//   planes [0, 262144)      : fp16 hi plane (131072 B) + fp16 lo plane (131072 B)
//   e2     [262144, 266240) : 1024 f32
// plane vector layout (B-fragment-ready, verified R5/R6): f16x8 index
//   ((g*2+k)*64 + l) for group g (16 codes), kstep k, lane l=q*16+ln holding
//   embed_plane[c=g*16+ln][j=k*32+q*8 .. +7].
#define WS_NEED 266240

// ============================ fast path ====================================
__global__ __launch_bounds__(256) void prep_kernel(
    const float* __restrict__ embed,
    _Float16* __restrict__ planes,
    float* __restrict__ e2g,
    float* __restrict__ counts,        // out_avg region  (zeroed here)
    float* __restrict__ distsum)       // out_commit slot (zeroed here)
{
    const int gidx = blockIdx.x * 256 + threadIdx.x;   // 8192 threads
    const int g  = gidx >> 7;
    const int k  = (gidx >> 6) & 1;
    const int l  = gidx & 63;
    const int q  = l >> 4;
    const int ln = l & 15;
    const int c  = g * 16 + ln;
    const int jb = k * 32 + q * 8;

    const float4 v0 = *(const float4*)(embed + (size_t)c * DIM + jb);
    const float4 v1 = *(const float4*)(embed + (size_t)c * DIM + jb + 4);
    const float xf[8] = {v0.x, v0.y, v0.z, v0.w, v1.x, v1.y, v1.z, v1.w};
    f16x8 h1, h2;
    #pragma unroll
    for (int e = 0; e < 8; ++e) {
        const _Float16 a = (_Float16)xf[e];
        h1[e] = a;
        h2[e] = (_Float16)(xf[e] - (float)a);   // exact residual
    }
    const int off = ((g * 2 + k) * 64 + l) * 8;
    *(f16x8*)(planes + off)         = h1;
    *(f16x8*)(planes + 65536 + off) = h2;

    if (gidx < KE) {
        const float4* rp = (const float4*)(embed + (size_t)gidx * DIM);
        float s = 0.f;
        #pragma unroll
        for (int i = 0; i < 16; ++i) {
            const float4 v = rp[i];
            s += v.x * v.x + v.y * v.y + v.z * v.z + v.w * v.w;
        }
        e2g[gidx]    = s;
        counts[gidx] = 0.f;
        if (gidx == 0) distsum[0] = 0.f;
    }
}

// Fused full-K argmin + gather, m=4 blocking.
// R2 post-mortem: kernels are B-load-rate/latency bound; arithmetic intensity
// per B-byte per wave is THE lever (R0 m=2: 46us, R2 m=1: 83us). This version:
// each wave owns 64 t-rows (A in 64 VGPRs, reused for all 1024 codes), so one
// 4KB B-group feeds 32 MFMAs (~512 cyc/SIMD of matrix work) with 4 independent
// 8-MFMA chains. Grid 256 blocks x 4 waves = 1 wave/SIMD (one wave saturates
// its matrix pipe at 1 MFMA/16cyc; low occupancy is expected/fine). L2 plane
// traffic cut 4x vs R2. Distance-1 double buffer, no hot-loop barriers.
// Numerics identical to verified R1/R2: same planes, same 8-MFMA accumulation
// order (small terms first), strict < + ascending index tie-break.
__global__ __launch_bounds__(256, 2) void argmin_fused(
    const float* __restrict__ x,       // [B][D][T]
    const _Float16* __restrict__ P,    // ws planes (hi at +0, lo at +131072 B)
    const float* __restrict__ e2g,     // ws e2
    const float* __restrict__ embed,
    float* __restrict__ out_q,
    float* __restrict__ out_idx,
    float* __restrict__ counts,
    float* __restrict__ distsum)
{
    __shared__ float e2s[1024];
    __shared__ int   ibest[256];
    __shared__ float x2s[256];
    __shared__ float mdsum[1];

    const int tid = threadIdx.x;
    const int l   = tid & 63;
    const int w   = tid >> 6;
    const int q   = l >> 4;
    const int ln  = l & 15;
    const int n0  = blockIdx.x << 8;   // 256 t per block
    const int b   = n0 >> 11;          // TT = 2048
    const int t0  = n0 & 2047;
    const int tb  = t0 + w * 64;       // this wave's 64-row t base

    if (tid == 0) mdsum[0] = 0.f;
    *(float4*)&e2s[tid * 4] = *(const float4*)(e2g + tid * 4);

    // ---- A fragments: fp16 split in registers (layout verified R5/R6) ----
    // t = tb + m*16 + ln, j = k*32 + q*8 + jj
    f16x8 af[2][4][2];                 // [plane][m][k]  = 64 VGPRs
    float x2p[4] = {0.f, 0.f, 0.f, 0.f};
    #pragma unroll
    for (int m = 0; m < 4; ++m)
        #pragma unroll
        for (int k = 0; k < 2; ++k)
            #pragma unroll
            for (int jj = 0; jj < 8; ++jj) {
                const int j = k * 32 + q * 8 + jj;
                const float xf = x[(size_t)(b * DIM + j) * TT + tb + m * 16 + ln];
                const _Float16 h1 = (_Float16)xf;
                af[0][m][k][jj] = h1;
                af[1][m][k][jj] = (_Float16)(xf - (float)h1);
                x2p[m] = fmaf(xf, xf, x2p[m]);
            }
    // full ||x_t||^2: sum the 4 q-quarters (lanes with same ln)
    #pragma unroll
    for (int m = 0; m < 4; ++m) {
        x2p[m] += __shfl_xor(x2p[m], 16);
        x2p[m] += __shfl_xor(x2p[m], 32);
        if (q == 0) x2s[w * 64 + m * 16 + ln] = x2p[m];
    }
    __syncthreads();                   // e2s, x2s ready (only pre-loop barrier)

    float bs[4][4];
    int   bi_[4][4];
    #pragma unroll
    for (int m = 0; m < 4; ++m)
        #pragma unroll
        for (int r = 0; r < 4; ++r) { bs[m][r] = FLT_MAX; bi_[m][r] = 0; }

    // B fragments for group gg (f16x8 view, verified R0 indexing):
    //   buf[0]=hi,k0  buf[1]=hi,k1  buf[2]=lo,k0  buf[3]=lo,k1
    // Overfetch at gg=64 stays inside ws (reads into lo plane / e2, unused).
    const f16x8* base = (const f16x8*)P + l;
#define LOADG(buf, gg) do {                                                  \
        const f16x8* gp_ = base + (gg) * 128;                                \
        buf[0] = gp_[0];                                                     \
        buf[1] = gp_[64];                                                    \
        buf[2] = gp_[8192];                                                  \
        buf[3] = gp_[8192 + 64];                                             \
    } while (0)

#define COMPUTE(buf, gg) do {                                                \
        const int   cgl_ = (gg) * 16 + ln;                                   \
        const float e2c_ = e2s[cgl_];                                        \
        _Pragma("unroll")                                                    \
        for (int m = 0; m < 4; ++m) {                                        \
            f32x4 C = {0.f, 0.f, 0.f, 0.f};                                  \
            /* small terms first for accuracy (verified R5/R6 ordering) */   \
            C = __builtin_amdgcn_mfma_f32_16x16x32_f16(af[1][m][0], buf[2], C, 0, 0, 0); \
            C = __builtin_amdgcn_mfma_f32_16x16x32_f16(af[1][m][1], buf[3], C, 0, 0, 0); \
            C = __builtin_amdgcn_mfma_f32_16x16x32_f16(af[1][m][0], buf[0], C, 0, 0, 0); \
            C = __builtin_amdgcn_mfma_f32_16x16x32_f16(af[1][m][1], buf[1], C, 0, 0, 0); \
            C = __builtin_amdgcn_mfma_f32_16x16x32_f16(af[0][m][0], buf[2], C, 0, 0, 0); \
            C = __builtin_amdgcn_mfma_f32_16x16x32_f16(af[0][m][1], buf[3], C, 0, 0, 0); \
            C = __builtin_amdgcn_mfma_f32_16x16x32_f16(af[0][m][0], buf[0], C, 0, 0, 0); \
            C = __builtin_amdgcn_mfma_f32_16x16x32_f16(af[0][m][1], buf[1], C, 0, 0, 0); \
            _Pragma("unroll")                                                \
            for (int r = 0; r < 4; ++r) {                                    \
                const float s = fmaf(-2.f, C[r], e2c_);                      \
                /* strict < + ascending c keeps lowest index on ties */      \
                if (s < bs[m][r]) { bs[m][r] = s; bi_[m][r] = cgl_; }        \
            }                                                                \
        }                                                                    \
    } while (0)

    // ---- hot loop: 64 groups of 16 codes, distance-1 double buffer ----
    f16x8 B0[4], B1[4];
    LOADG(B0, 0);
    #pragma unroll 1
    for (int g = 0; g < 64; g += 2) {
        LOADG(B1, g + 1);              // lands while COMPUTE(B0) runs
        COMPUTE(B0, g);
        LOADG(B0, g + 2);              // g=62 -> gg=64: harmless overfetch
        COMPUTE(B1, g + 1);
    }
#undef LOADG
#undef COMPUTE

    // ---- reduce over the 16 code-columns; block-local result is final ----
    float mdloc = 0.f;
    #pragma unroll
    for (int m = 0; m < 4; ++m)
        #pragma unroll
        for (int r = 0; r < 4; ++r) {
            float s = bs[m][r]; int i = bi_[m][r];
            #pragma unroll
            for (int mask = 1; mask < 16; mask <<= 1) {
                const float s2 = __shfl_xor(s, mask);
                const int   i2 = __shfl_xor(i, mask);
                if (s2 < s || (s2 == s && i2 < i)) { s = s2; i = i2; }
            }
            if (ln == 0) {
                const int t_loc = w * 64 + m * 16 + q * 4 + r;   // C-row map
                ibest[t_loc] = i;
                out_idx[n0 + t_loc] = (float)i;
                atomicAdd(&counts[i], 1.0f);
                mdloc += x2s[t_loc] + s;            // ||x||^2 + e^2 - 2 x.e
            }
        }
    if (ln == 0) atomicAdd(&mdsum[0], mdloc);
    __syncthreads();
    if (tid == 0) atomicAdd(distsum, mdsum[0]);

    // ---- gather: out_q[b][j][t0+tt] = embed[ibest[tt]][j] (embed L2-hot) ---
    #pragma unroll
    for (int p = 0; p < 64; ++p) {
        const int f  = p * 256 + tid;
        const int j  = f >> 8;
        const int tt = f & 255;
        out_q[(size_t)(b * DIM + j) * TT + t0 + tt] =
            embed[(size_t)ibest[tt] * DIM + j];
    }
}

// ======================= fallback path (Round-5, passed) ====================
#define EP_ROW   72
#define EP_PLANE 4608
#define SMEM_BYTES (36864 + 4096 + 512 + 512 + 16)

__global__ __launch_bounds__(256, 2) void argmin_fb(
    const float* __restrict__ x, const float* __restrict__ embed,
    float* __restrict__ out_q, float* __restrict__ out_idx,
    float* __restrict__ counts, float* __restrict__ distsum)
{
    __shared__ __align__(16) char smem[SMEM_BYTES];
    _Float16* ep  = (_Float16*)smem;
    float* e2s    = (float*)(smem + 36864);
    float* x2s    = (float*)(smem + 36864 + 4096);
    int*   ibest  = (int*)  (smem + 36864 + 4608);
    float* mdsum  = (float*)(smem + 36864 + 5120);

    const int tid = threadIdx.x;
    const int l   = tid & 63;
    const int w   = tid >> 6;
    const int q   = l >> 4;
    const int ln  = l & 15;
    const int bid = blockIdx.x;
    const int b   = bid >> 4;
    const int t0  = (bid & 15) << 7;

    if (tid == 0) mdsum[0] = 0.f;
    #pragma unroll
    for (int pass = 0; pass < 4; ++pass) {
        const int c = pass * 256 + tid;
        const float4* rp = (const float4*)(embed + (size_t)c * DIM);
        float s = 0.f;
        #pragma unroll
        for (int i = 0; i < 16; ++i) {
            const float4 v = rp[i];
            s += v.x * v.x + v.y * v.y + v.z * v.z + v.w * v.w;
        }
        e2s[c] = s;
    }
    f16x8 af[2][2][2];
    float x2p[2] = {0.f, 0.f};
    #pragma unroll
    for (int m = 0; m < 2; ++m)
        #pragma unroll
        for (int k = 0; k < 2; ++k)
            #pragma unroll
            for (int jj = 0; jj < 8; ++jj) {
                const int j = k * 32 + q * 8 + jj;
                const float xf = x[(size_t)(b * DIM + j) * TT + t0 + w * 32 + m * 16 + ln];
                const _Float16 h1 = (_Float16)xf;
                af[0][m][k][jj] = h1;
                af[1][m][k][jj] = (_Float16)(xf - (float)h1);
                x2p[m] = fmaf(xf, xf, x2p[m]);
            }
    #pragma unroll
    for (int m = 0; m < 2; ++m) {
        x2p[m] += __shfl_xor(x2p[m], 16);
        x2p[m] += __shfl_xor(x2p[m], 32);
    }
    if (q == 0) { x2s[w * 32 + ln] = x2p[0]; x2s[w * 32 + 16 + ln] = x2p[1]; }
    {
        #pragma unroll
        for (int pass = 0; pass < 4; ++pass) {
            const int c_loc = (tid >> 4) + pass * 16;
            const int j4    = (tid & 15) * 4;
            const float4 v = *(const float4*)(embed + (size_t)c_loc * DIM + j4);
            f16x4 h1, h2;
            h1[0] = (_Float16)v.x; h2[0] = (_Float16)(v.x - (float)h1[0]);
            h1[1] = (_Float16)v.y; h2[1] = (_Float16)(v.y - (float)h1[1]);
            h1[2] = (_Float16)v.z; h2[2] = (_Float16)(v.z - (float)h1[2]);
            h1[3] = (_Float16)v.w; h2[3] = (_Float16)(v.w - (float)h1[3]);
            *(f16x4*)(ep + c_loc * EP_ROW + j4)            = h1;
            *(f16x4*)(ep + EP_PLANE + c_loc * EP_ROW + j4) = h2;
        }
    }
    __syncthreads();
    float bs[2][4]; int bi[2][4];
    #pragma unroll
    for (int m = 0; m < 2; ++m)
        #pragma unroll
        for (int r = 0; r < 4; ++r) { bs[m][r] = FLT_MAX; bi[m][r] = 0; }
    for (int kc = 0; kc < 16; ++kc) {
        const int cur = kc & 1, nxt = cur ^ 1;
        float4 ev[4];
        if (kc < 15)
            #pragma unroll
            for (int pass = 0; pass < 4; ++pass) {
                const int c_loc = (tid >> 4) + pass * 16;
                const int j4    = (tid & 15) * 4;
                ev[pass] = *(const float4*)(embed + (size_t)((kc + 1) * 64 + c_loc) * DIM + j4);
            }
        const _Float16* p1 = ep + cur * 2 * EP_PLANE;
        const _Float16* p2 = p1 + EP_PLANE;
        #pragma unroll
        for (int n = 0; n < 4; ++n) {
            const int coff = (n * 16 + ln) * EP_ROW + q * 8;
            const f16x8 b1k0 = *(const f16x8*)(p1 + coff);
            const f16x8 b1k1 = *(const f16x8*)(p1 + coff + 32);
            const f16x8 b2k0 = *(const f16x8*)(p2 + coff);
            const f16x8 b2k1 = *(const f16x8*)(p2 + coff + 32);
            const int   c_lane = kc * 64 + n * 16 + ln;
            const float e2c    = e2s[c_lane];
            #pragma unroll
            for (int m = 0; m < 2; ++m) {
                f32x4 C = {0.f, 0.f, 0.f, 0.f};
                C = __builtin_amdgcn_mfma_f32_16x16x32_f16(af[1][m][0], b2k0, C, 0, 0, 0);
                C = __builtin_amdgcn_mfma_f32_16x16x32_f16(af[1][m][1], b2k1, C, 0, 0, 0);
                C = __builtin_amdgcn_mfma_f32_16x16x32_f16(af[1][m][0], b1k0, C, 0, 0, 0);
                C = __builtin_amdgcn_mfma_f32_16x16x32_f16(af[1][m][1], b1k1, C, 0, 0, 0);
                C = __builtin_amdgcn_mfma_f32_16x16x32_f16(af[0][m][0], b2k0, C, 0, 0, 0);
                C = __builtin_amdgcn_mfma_f32_16x16x32_f16(af[0][m][1], b2k1, C, 0, 0, 0);
                C = __builtin_amdgcn_mfma_f32_16x16x32_f16(af[0][m][0], b1k0, C, 0, 0, 0);
                C = __builtin_amdgcn_mfma_f32_16x16x32_f16(af[0][m][1], b1k1, C, 0, 0, 0);
                #pragma unroll
                for (int r = 0; r < 4; ++r) {
                    const float s = fmaf(-2.f, C[r], e2c);
                    if (s < bs[m][r]) { bs[m][r] = s; bi[m][r] = c_lane; }
                }
            }
        }
        if (kc < 15) {
            _Float16* w1 = ep + nxt * 2 * EP_PLANE;
            _Float16* w2 = w1 + EP_PLANE;
            #pragma unroll
            for (int pass = 0; pass < 4; ++pass) {
                const int c_loc = (tid >> 4) + pass * 16;
                const int j4    = (tid & 15) * 4;
                const float4 v = ev[pass];
                f16x4 h1, h2;
                h1[0] = (_Float16)v.x; h2[0] = (_Float16)(v.x - (float)h1[0]);
                h1[1] = (_Float16)v.y; h2[1] = (_Float16)(v.y - (float)h1[1]);
                h1[2] = (_Float16)v.z; h2[2] = (_Float16)(v.z - (float)h1[2]);
                h1[3] = (_Float16)v.w; h2[3] = (_Float16)(v.w - (float)h1[3]);
                *(f16x4*)(w1 + c_loc * EP_ROW + j4) = h1;
                *(f16x4*)(w2 + c_loc * EP_ROW + j4) = h2;
            }
        }
        __syncthreads();
    }
    float mdloc = 0.f;
    #pragma unroll
    for (int m = 0; m < 2; ++m)
        #pragma unroll
        for (int r = 0; r < 4; ++r) {
            float s = bs[m][r]; int i = bi[m][r];
            #pragma unroll
            for (int mask = 1; mask < 16; mask <<= 1) {
                const float s2 = __shfl_xor(s, mask);
                const int   i2 = __shfl_xor(i, mask);
                if (s2 < s || (s2 == s && i2 < i)) { s = s2; i = i2; }
            }
            if (ln == 0) {
                const int t_loc = w * 32 + m * 16 + q * 4 + r;
                ibest[t_loc] = i;
                out_idx[b * TT + t0 + t_loc] = (float)i;
                atomicAdd(&counts[i], 1.0f);
                mdloc += x2s[t_loc] + s;
            }
        }
    if (ln == 0) atomicAdd(mdsum, mdloc);
    __syncthreads();
    if (tid == 0) atomicAdd(distsum, mdsum[0]);
    #pragma unroll
    for (int p = 0; p < 32; ++p) {
        const int f  = p * 256 + tid;
        const int j  = f >> 7;
        const int tt = f & 127;
        out_q[(size_t)(b * DIM + j) * TT + t0 + tt] =
            embed[(size_t)ibest[tt] * DIM + j];
    }
}

// finalize: in-place counts->avg_probs, perplexity, usage, commitment
__global__ __launch_bounds__(1024) void finalize_kernel(
    float* __restrict__ avg, float* __restrict__ commit_slot,
    float* __restrict__ out_perp, float* __restrict__ out_usage)
{
    __shared__ float s_ent[1024];
    __shared__ float s_use[1024];
    const int k = threadIdx.x;
    const float p = avg[k] * (1.0f / (float)NTOT);
    avg[k] = p;
    s_ent[k] = p * logf(p + 1e-10f);
    s_use[k] = p * logf(p * 1024.f + 1e-10f);
    __syncthreads();
    for (int off = 512; off > 0; off >>= 1) {
        if (k < off) { s_ent[k] += s_ent[k + off]; s_use[k] += s_use[k + off]; }
        __syncthreads();
    }
    if (k == 0) {
        const float ds = commit_slot[0];
        *out_perp      = expf(-s_ent[0]);
        *out_usage     = s_use[0];
        commit_slot[0] = 0.25f * ds * (1.0f / ((float)NTOT * (float)DIM));
    }
}

extern "C" void kernel_launch(void* const* d_in, const int* in_sizes, int n_in,
                              void* d_out, int out_size, void* d_ws, size_t ws_size,
                              hipStream_t stream) {
    const float* x     = (const float*)d_in[0];
    const float* embed = (const float*)d_in[1];

    float* out        = (float*)d_out;
    float* out_q      = out;             // 4194304
    float* out_commit = out + 4194304;   // distsum accumulator first
    float* out_perp   = out + 4194305;
    float* out_avg    = out + 4194306;   // counts accumulator first
    float* out_idx    = out + 4195330;
    // usage at out + 4260866

    if (ws_size >= WS_NEED) {
        _Float16* planes = (_Float16*)d_ws;
        float*    e2g    = (float*)((char*)d_ws + 262144);
        prep_kernel<<<32, 256, 0, stream>>>(embed, planes, e2g, out_avg, out_commit);
        argmin_fused<<<256, 256, 0, stream>>>(x, planes, e2g, embed,
                                              out_q, out_idx, out_avg, out_commit);
    } else {
        hipMemsetAsync(out_commit, 0, 1026 * sizeof(float), stream);
        argmin_fb<<<512, 256, 0, stream>>>(x, embed, out_q, out_idx, out_avg, out_commit);
    }
    finalize_kernel<<<1, 1024, 0, stream>>>(out_avg, out_commit, out_perp, out + 4260866);
}

// Round 4
// 141.647 us; speedup vs baseline: 1.0969x; 1.0969x over previous
//
#include <hip/hip_runtime.h>
#include <cfloat>
#include <cmath>

#define DIM 64
#define TT 2048
#define NTOT 65536
#define KE 1024

typedef _Float16 f16x8 __attribute__((ext_vector_type(8)));
typedef _Float16 f16x4 __attribute__((ext_vector_type(4)));
typedef float    f32x4 __attribute__((ext_vector_type(4)));

// ws layout (bytes):
//   planes [0, 262144)      : fp16 hi plane (131072 B) + fp16 lo plane (131072 B)
//   e2     [262144, 266240) : 1024 f32
// plane vector layout (B-fragment-ready, verified R5/R6): f16x8 index
//   ((g*2+k)*64 + l) for group g (16 codes), kstep k, lane l=q*16+ln holding
//   embed_plane[c=g*16+ln][j=k*32+q*8 .. +7].
#define WS_NEED 266240

// async global->LDS, 16B per lane; LDS dest is wave-uniform base + lane*16
__device__ __forceinline__ void gload_lds16(const void* g, void* l) {
    __builtin_amdgcn_global_load_lds(
        (const __attribute__((address_space(1))) unsigned int*)g,
        (__attribute__((address_space(3))) unsigned int*)l, 16, 0, 0);
}

// ============================ fast path ====================================
__global__ __launch_bounds__(256) void prep_kernel(
    const float* __restrict__ embed,
    _Float16* __restrict__ planes,
    float* __restrict__ e2g,
    float* __restrict__ counts,        // out_avg region  (zeroed here)
    float* __restrict__ distsum)       // out_commit slot (zeroed here)
{
    const int gidx = blockIdx.x * 256 + threadIdx.x;   // 8192 threads
    const int g  = gidx >> 7;
    const int k  = (gidx >> 6) & 1;
    const int l  = gidx & 63;
    const int q  = l >> 4;
    const int ln = l & 15;
    const int c  = g * 16 + ln;
    const int jb = k * 32 + q * 8;

    const float4 v0 = *(const float4*)(embed + (size_t)c * DIM + jb);
    const float4 v1 = *(const float4*)(embed + (size_t)c * DIM + jb + 4);
    const float xf[8] = {v0.x, v0.y, v0.z, v0.w, v1.x, v1.y, v1.z, v1.w};
    f16x8 h1, h2;
    #pragma unroll
    for (int e = 0; e < 8; ++e) {
        const _Float16 a = (_Float16)xf[e];
        h1[e] = a;
        h2[e] = (_Float16)(xf[e] - (float)a);   // exact residual
    }
    const int off = ((g * 2 + k) * 64 + l) * 8;
    *(f16x8*)(planes + off)         = h1;
    *(f16x8*)(planes + 65536 + off) = h2;

    if (gidx < KE) {
        const float4* rp = (const float4*)(embed + (size_t)gidx * DIM);
        float s = 0.f;
        #pragma unroll
        for (int i = 0; i < 16; ++i) {
            const float4 v = rp[i];
            s += v.x * v.x + v.y * v.y + v.z * v.z + v.w * v.w;
        }
        e2g[gidx]    = s;
        counts[gidx] = 0.f;
        if (gidx == 0) distsum[0] = 0.f;
    }
}

// Fused full-K argmin + gather, LDS-shared B with LARGE barrier windows.
// R0/R2 post-mortem: direct-load versions run at a fixed ~12 TB/s effective
// L2 rate -> time scales with per-wave B traffic (R0 512MB/46us, R2 1GB/83us).
// R3 cut traffic but 1 block/CU couldn't hide latency. R1 shared via LDS but
// paid a vmcnt(0) barrier drain every 2 groups (32 drains).
// This version: 512 blocks (2/CU, 8 waves/CU TLP), m=2 per wave (R0-proven),
// B staged in 8-group (32KB) chunks, double-buffered -> only 8 barrier
// windows; next chunk's global_load_lds DMA issues at window START, so at the
// closing barrier the loads are ~2500 cyc old (latency hidden, only delivery
// remains, covered 2x by compute). Global B traffic: 512 x 256KB = 128MB.
// Numerics identical to verified R0/R1/R2: same planes, same 8-MFMA
// accumulation order (small terms first), strict < + ascending index ties.
__global__ __launch_bounds__(256, 2) void argmin_fused(
    const float* __restrict__ x,       // [B][D][T]
    const _Float16* __restrict__ P,    // ws planes (hi at +0, lo at +131072 B)
    const float* __restrict__ e2g,     // ws e2
    const float* __restrict__ embed,
    float* __restrict__ out_q,
    float* __restrict__ out_idx,
    float* __restrict__ counts,
    float* __restrict__ distsum)
{
    // chunk image = byte-identical copy of 16KB of hi plane + 16KB of lo
    // plane (8 groups): group gl at [gl*2048), k at +k*1024, lane l at +l*16;
    // lo half at +16384. ds_read_b128 stride-16B across lanes: conflict-free.
    __shared__ __align__(16) char lds_b[2][32768];
    __shared__ float e2s[1024];
    __shared__ int   ibest[128];
    __shared__ float x2s[128];
    __shared__ float mdsum[1];

    const int tid = threadIdx.x;
    const int l   = tid & 63;
    const int w   = tid >> 6;
    const int q   = l >> 4;
    const int ln  = l & 15;
    const int bid = blockIdx.x;        // 512 blocks: 32 b x 16 t-tiles
    const int b   = bid >> 4;
    const int t0  = (bid & 15) << 7;   // 128 t per block

    const char* Pb = (const char*)P;
    // stage chunk cc (groups 8cc..8cc+7) into buffer bi: 8 DMA per thread
#define STAGE_CHUNK(bi, cc) do {                                             \
        const char* hs_ = Pb + (cc) * 16384;                                 \
        const char* ls_ = Pb + 131072 + (cc) * 16384;                        \
        char* db_ = &lds_b[bi][0];                                           \
        _Pragma("unroll")                                                    \
        for (int r_ = 0; r_ < 4; ++r_) {                                     \
            gload_lds16(hs_ + r_ * 4096 + tid * 16,                          \
                        db_ + r_ * 4096 + tid * 16);                         \
            gload_lds16(ls_ + r_ * 4096 + tid * 16,                          \
                        db_ + 16384 + r_ * 4096 + tid * 16);                 \
        }                                                                    \
    } while (0)

    STAGE_CHUNK(0, 0);                 // DMA runs under the whole prologue

    if (tid == 0) mdsum[0] = 0.f;
    *(float4*)&e2s[tid * 4] = *(const float4*)(e2g + tid * 4);

    // ---- A fragments: fp16 split in registers (layout verified R5/R6) ----
    // t = t0 + w*32 + m*16 + ln, j = k*32 + q*8 + jj
    f16x8 af[2][2][2];                 // [plane][m][k]
    float x2p[2] = {0.f, 0.f};
    #pragma unroll
    for (int m = 0; m < 2; ++m)
        #pragma unroll
        for (int k = 0; k < 2; ++k)
            #pragma unroll
            for (int jj = 0; jj < 8; ++jj) {
                const int j = k * 32 + q * 8 + jj;
                const float xf = x[(size_t)(b * DIM + j) * TT + t0 + w * 32 + m * 16 + ln];
                const _Float16 h1 = (_Float16)xf;
                af[0][m][k][jj] = h1;
                af[1][m][k][jj] = (_Float16)(xf - (float)h1);
                x2p[m] = fmaf(xf, xf, x2p[m]);
            }
    // full ||x_t||^2: sum the 4 q-quarters (lanes with same ln)
    #pragma unroll
    for (int m = 0; m < 2; ++m) {
        x2p[m] += __shfl_xor(x2p[m], 16);
        x2p[m] += __shfl_xor(x2p[m], 32);
    }
    if (q == 0) { x2s[w * 32 + ln] = x2p[0]; x2s[w * 32 + 16 + ln] = x2p[1]; }
    __syncthreads();                   // e2s, x2s, chunk0 DMA all drained

    float bs[2][4];
    int   bi_[2][4];
    #pragma unroll
    for (int m = 0; m < 2; ++m)
        #pragma unroll
        for (int r = 0; r < 4; ++r) { bs[m][r] = FLT_MAX; bi_[m][r] = 0; }

    // ---- hot loop: 8 chunks x 8 groups of 16 codes = all 1024 codes ----
    #pragma unroll 1
    for (int ci = 0; ci < 8; ++ci) {
        const int cur = ci & 1;
        if (ci < 7) STAGE_CHUNK(cur ^ 1, ci + 1);   // issue at window START
        #pragma unroll
        for (int gl = 0; gl < 8; ++gl) {
            const char* gb = &lds_b[cur][0] + gl * 2048 + l * 16;
            const f16x8 b1k0 = *(const f16x8*)(gb);
            const f16x8 b1k1 = *(const f16x8*)(gb + 1024);
            const f16x8 b2k0 = *(const f16x8*)(gb + 16384);
            const f16x8 b2k1 = *(const f16x8*)(gb + 16384 + 1024);
            const int   cgl  = (ci * 8 + gl) * 16 + ln;
            const float e2c  = e2s[cgl];
            #pragma unroll
            for (int m = 0; m < 2; ++m) {
                f32x4 C = {0.f, 0.f, 0.f, 0.f};
                // small terms first for accuracy (verified R5/R6 ordering)
                C = __builtin_amdgcn_mfma_f32_16x16x32_f16(af[1][m][0], b2k0, C, 0, 0, 0);
                C = __builtin_amdgcn_mfma_f32_16x16x32_f16(af[1][m][1], b2k1, C, 0, 0, 0);
                C = __builtin_amdgcn_mfma_f32_16x16x32_f16(af[1][m][0], b1k0, C, 0, 0, 0);
                C = __builtin_amdgcn_mfma_f32_16x16x32_f16(af[1][m][1], b1k1, C, 0, 0, 0);
                C = __builtin_amdgcn_mfma_f32_16x16x32_f16(af[0][m][0], b2k0, C, 0, 0, 0);
                C = __builtin_amdgcn_mfma_f32_16x16x32_f16(af[0][m][1], b2k1, C, 0, 0, 0);
                C = __builtin_amdgcn_mfma_f32_16x16x32_f16(af[0][m][0], b1k0, C, 0, 0, 0);
                C = __builtin_amdgcn_mfma_f32_16x16x32_f16(af[0][m][1], b1k1, C, 0, 0, 0);
                #pragma unroll
                for (int r = 0; r < 4; ++r) {
                    const float s = fmaf(-2.f, C[r], e2c);
                    // strict < + ascending c keeps lowest index on ties
                    if (s < bs[m][r]) { bs[m][r] = s; bi_[m][r] = cgl; }
                }
            }
        }
        __syncthreads();               // drains next-chunk DMA (issued ~2500cyc ago)
    }
#undef STAGE_CHUNK

    // ---- reduce over the 16 code-columns; block-local result is final ----
    float mdloc = 0.f;
    #pragma unroll
    for (int m = 0; m < 2; ++m)
        #pragma unroll
        for (int r = 0; r < 4; ++r) {
            float s = bs[m][r]; int i = bi_[m][r];
            #pragma unroll
            for (int mask = 1; mask < 16; mask <<= 1) {
                const float s2 = __shfl_xor(s, mask);
                const int   i2 = __shfl_xor(i, mask);
                if (s2 < s || (s2 == s && i2 < i)) { s = s2; i = i2; }
            }
            if (ln == 0) {
                const int t_loc = w * 32 + m * 16 + q * 4 + r;   // C-row map
                ibest[t_loc] = i;
                out_idx[b * TT + t0 + t_loc] = (float)i;
                atomicAdd(&counts[i], 1.0f);
                mdloc += x2s[t_loc] + s;            // ||x||^2 + e^2 - 2 x.e
            }
        }
    if (ln == 0) atomicAdd(&mdsum[0], mdloc);
    __syncthreads();
    if (tid == 0) atomicAdd(distsum, mdsum[0]);

    // ---- gather: out_q[b][j][t0+tt] = embed[ibest[tt]][j] (embed L2-hot) ---
    #pragma unroll
    for (int p = 0; p < 32; ++p) {
        const int f  = p * 256 + tid;
        const int j  = f >> 7;
        const int tt = f & 127;
        out_q[(size_t)(b * DIM + j) * TT + t0 + tt] =
            embed[(size_t)ibest[tt] * DIM + j];
    }
}

// ======================= fallback path (Round-5, passed) ====================
#define EP_ROW   72
#define EP_PLANE 4608
#define SMEM_BYTES (36864 + 4096 + 512 + 512 + 16)

__global__ __launch_bounds__(256, 2) void argmin_fb(
    const float* __restrict__ x, const float* __restrict__ embed,
    float* __restrict__ out_q, float* __restrict__ out_idx,
    float* __restrict__ counts, float* __restrict__ distsum)
{
    __shared__ __align__(16) char smem[SMEM_BYTES];
    _Float16* ep  = (_Float16*)smem;
    float* e2s    = (float*)(smem + 36864);
    float* x2s    = (float*)(smem + 36864 + 4096);
    int*   ibest  = (int*)  (smem + 36864 + 4608);
    float* mdsum  = (float*)(smem + 36864 + 5120);

    const int tid = threadIdx.x;
    const int l   = tid & 63;
    const int w   = tid >> 6;
    const int q   = l >> 4;
    const int ln  = l & 15;
    const int bid = blockIdx.x;
    const int b   = bid >> 4;
    const int t0  = (bid & 15) << 7;

    if (tid == 0) mdsum[0] = 0.f;
    #pragma unroll
    for (int pass = 0; pass < 4; ++pass) {
        const int c = pass * 256 + tid;
        const float4* rp = (const float4*)(embed + (size_t)c * DIM);
        float s = 0.f;
        #pragma unroll
        for (int i = 0; i < 16; ++i) {
            const float4 v = rp[i];
            s += v.x * v.x + v.y * v.y + v.z * v.z + v.w * v.w;
        }
        e2s[c] = s;
    }
    f16x8 af[2][2][2];
    float x2p[2] = {0.f, 0.f};
    #pragma unroll
    for (int m = 0; m < 2; ++m)
        #pragma unroll
        for (int k = 0; k < 2; ++k)
            #pragma unroll
            for (int jj = 0; jj < 8; ++jj) {
                const int j = k * 32 + q * 8 + jj;
                const float xf = x[(size_t)(b * DIM + j) * TT + t0 + w * 32 + m * 16 + ln];
                const _Float16 h1 = (_Float16)xf;
                af[0][m][k][jj] = h1;
                af[1][m][k][jj] = (_Float16)(xf - (float)h1);
                x2p[m] = fmaf(xf, xf, x2p[m]);
            }
    #pragma unroll
    for (int m = 0; m < 2; ++m) {
        x2p[m] += __shfl_xor(x2p[m], 16);
        x2p[m] += __shfl_xor(x2p[m], 32);
    }
    if (q == 0) { x2s[w * 32 + ln] = x2p[0]; x2s[w * 32 + 16 + ln] = x2p[1]; }
    {
        #pragma unroll
        for (int pass = 0; pass < 4; ++pass) {
            const int c_loc = (tid >> 4) + pass * 16;
            const int j4    = (tid & 15) * 4;
            const float4 v = *(const float4*)(embed + (size_t)c_loc * DIM + j4);
            f16x4 h1, h2;
            h1[0] = (_Float16)v.x; h2[0] = (_Float16)(v.x - (float)h1[0]);
            h1[1] = (_Float16)v.y; h2[1] = (_Float16)(v.y - (float)h1[1]);
            h1[2] = (_Float16)v.z; h2[2] = (_Float16)(v.z - (float)h1[2]);
            h1[3] = (_Float16)v.w; h2[3] = (_Float16)(v.w - (float)h1[3]);
            *(f16x4*)(ep + c_loc * EP_ROW + j4)            = h1;
            *(f16x4*)(ep + EP_PLANE + c_loc * EP_ROW + j4) = h2;
        }
    }
    __syncthreads();
    float bs[2][4]; int bi[2][4];
    #pragma unroll
    for (int m = 0; m < 2; ++m)
        #pragma unroll
        for (int r = 0; r < 4; ++r) { bs[m][r] = FLT_MAX; bi[m][r] = 0; }
    for (int kc = 0; kc < 16; ++kc) {
        const int cur = kc & 1, nxt = cur ^ 1;
        float4 ev[4];
        if (kc < 15)
            #pragma unroll
            for (int pass = 0; pass < 4; ++pass) {
                const int c_loc = (tid >> 4) + pass * 16;
                const int j4    = (tid & 15) * 4;
                ev[pass] = *(const float4*)(embed + (size_t)((kc + 1) * 64 + c_loc) * DIM + j4);
            }
        const _Float16* p1 = ep + cur * 2 * EP_PLANE;
        const _Float16* p2 = p1 + EP_PLANE;
        #pragma unroll
        for (int n = 0; n < 4; ++n) {
            const int coff = (n * 16 + ln) * EP_ROW + q * 8;
            const f16x8 b1k0 = *(const f16x8*)(p1 + coff);
            const f16x8 b1k1 = *(const f16x8*)(p1 + coff + 32);
            const f16x8 b2k0 = *(const f16x8*)(p2 + coff);
            const f16x8 b2k1 = *(const f16x8*)(p2 + coff + 32);
            const int   c_lane = kc * 64 + n * 16 + ln;
            const float e2c    = e2s[c_lane];
            #pragma unroll
            for (int m = 0; m < 2; ++m) {
                f32x4 C = {0.f, 0.f, 0.f, 0.f};
                C = __builtin_amdgcn_mfma_f32_16x16x32_f16(af[1][m][0], b2k0, C, 0, 0, 0);
                C = __builtin_amdgcn_mfma_f32_16x16x32_f16(af[1][m][1], b2k1, C, 0, 0, 0);
                C = __builtin_amdgcn_mfma_f32_16x16x32_f16(af[1][m][0], b1k0, C, 0, 0, 0);
                C = __builtin_amdgcn_mfma_f32_16x16x32_f16(af[1][m][1], b1k1, C, 0, 0, 0);
                C = __builtin_amdgcn_mfma_f32_16x16x32_f16(af[0][m][0], b2k0, C, 0, 0, 0);
                C = __builtin_amdgcn_mfma_f32_16x16x32_f16(af[0][m][1], b2k1, C, 0, 0, 0);
                C = __builtin_amdgcn_mfma_f32_16x16x32_f16(af[0][m][0], b1k0, C, 0, 0, 0);
                C = __builtin_amdgcn_mfma_f32_16x16x32_f16(af[0][m][1], b1k1, C, 0, 0, 0);
                #pragma unroll
                for (int r = 0; r < 4; ++r) {
                    const float s = fmaf(-2.f, C[r], e2c);
                    if (s < bs[m][r]) { bs[m][r] = s; bi[m][r] = c_lane; }
                }
            }
        }
        if (kc < 15) {
            _Float16* w1 = ep + nxt * 2 * EP_PLANE;
            _Float16* w2 = w1 + EP_PLANE;
            #pragma unroll
            for (int pass = 0; pass < 4; ++pass) {
                const int c_loc = (tid >> 4) + pass * 16;
                const int j4    = (tid & 15) * 4;
                const float4 v = ev[pass];
                f16x4 h1, h2;
                h1[0] = (_Float16)v.x; h2[0] = (_Float16)(v.x - (float)h1[0]);
                h1[1] = (_Float16)v.y; h2[1] = (_Float16)(v.y - (float)h1[1]);
                h1[2] = (_Float16)v.z; h2[2] = (_Float16)(v.z - (float)h1[2]);
                h1[3] = (_Float16)v.w; h2[3] = (_Float16)(v.w - (float)h1[3]);
                *(f16x4*)(w1 + c_loc * EP_ROW + j4) = h1;
                *(f16x4*)(w2 + c_loc * EP_ROW + j4) = h2;
            }
        }
        __syncthreads();
    }
    float mdloc = 0.f;
    #pragma unroll
    for (int m = 0; m < 2; ++m)
        #pragma unroll
        for (int r = 0; r < 4; ++r) {
            float s = bs[m][r]; int i = bi[m][r];
            #pragma unroll
            for (int mask = 1; mask < 16; mask <<= 1) {
                const float s2 = __shfl_xor(s, mask);
                const int   i2 = __shfl_xor(i, mask);
                if (s2 < s || (s2 == s && i2 < i)) { s = s2; i = i2; }
            }
            if (ln == 0) {
                const int t_loc = w * 32 + m * 16 + q * 4 + r;
                ibest[t_loc] = i;
                out_idx[b * TT + t0 + t_loc] = (float)i;
                atomicAdd(&counts[i], 1.0f);
                mdloc += x2s[t_loc] + s;
            }
        }
    if (ln == 0) atomicAdd(mdsum, mdloc);
    __syncthreads();
    if (tid == 0) atomicAdd(distsum, mdsum[0]);
    #pragma unroll
    for (int p = 0; p < 32; ++p) {
        const int f  = p * 256 + tid;
        const int j  = f >> 7;
        const int tt = f & 127;
        out_q[(size_t)(b * DIM + j) * TT + t0 + tt] =
            embed[(size_t)ibest[tt] * DIM + j];
    }
}

// finalize: in-place counts->avg_probs, perplexity, usage, commitment
__global__ __launch_bounds__(1024) void finalize_kernel(
    float* __restrict__ avg, float* __restrict__ commit_slot,
    float* __restrict__ out_perp, float* __restrict__ out_usage)
{
    __shared__ float s_ent[1024];
    __shared__ float s_use[1024];
    const int k = threadIdx.x;
    const float p = avg[k] * (1.0f / (float)NTOT);
    avg[k] = p;
    s_ent[k] = p * logf(p + 1e-10f);
    s_use[k] = p * logf(p * 1024.f + 1e-10f);
    __syncthreads();
    for (int off = 512; off > 0; off >>= 1) {
        if (k < off) { s_ent[k] += s_ent[k + off]; s_use[k] += s_use[k + off]; }
        __syncthreads();
    }
    if (k == 0) {
        const float ds = commit_slot[0];
        *out_perp      = expf(-s_ent[0]);
        *out_usage     = s_use[0];
        commit_slot[0] = 0.25f * ds * (1.0f / ((float)NTOT * (float)DIM));
    }
}

extern "C" void kernel_launch(void* const* d_in, const int* in_sizes, int n_in,
                              void* d_out, int out_size, void* d_ws, size_t ws_size,
                              hipStream_t stream) {
    const float* x     = (const float*)d_in[0];
    const float* embed = (const float*)d_in[1];

    float* out        = (float*)d_out;
    float* out_q      = out;             // 4194304
    float* out_commit = out + 4194304;   // distsum accumulator first
    float* out_perp   = out + 4194305;
    float* out_avg    = out + 4194306;   // counts accumulator first
    float* out_idx    = out + 4195330;
    // usage at out + 4260866

    if (ws_size >= WS_NEED) {
        _Float16* planes = (_Float16*)d_ws;
        float*    e2g    = (float*)((char*)d_ws + 262144);
        prep_kernel<<<32, 256, 0, stream>>>(embed, planes, e2g, out_avg, out_commit);
        argmin_fused<<<512, 256, 0, stream>>>(x, planes, e2g, embed,
                                              out_q, out_idx, out_avg, out_commit);
    } else {
        hipMemsetAsync(out_commit, 0, 1026 * sizeof(float), stream);
        argmin_fb<<<512, 256, 0, stream>>>(x, embed, out_q, out_idx, out_avg, out_commit);
    }
    finalize_kernel<<<1, 1024, 0, stream>>>(out_avg, out_commit, out_perp, out + 4260866);
}

// Round 5
// 133.414 us; speedup vs baseline: 1.1646x; 1.0617x over previous
//
#include <hip/hip_runtime.h>
#include <cfloat>
#include <cmath>

#define DIM 64
#define TT 2048
#define NTOT 65536
#define KE 1024

typedef _Float16 f16x8 __attribute__((ext_vector_type(8)));
typedef _Float16 f16x4 __attribute__((ext_vector_type(4)));
typedef float    f32x4 __attribute__((ext_vector_type(4)));

// ws layout (bytes):
//   planes [0, 262144)      : fp16 hi plane (131072 B) + fp16 lo plane (131072 B)
//   e2     [262144, 266240) : 1024 f32
// plane vector layout (B-fragment-ready, verified R5/R6): f16x8 index
//   ((g*2+k)*64 + l) for group g (16 codes), kstep k, lane l=q*16+ln holding
//   embed_plane[c=g*16+ln][j=k*32+q*8 .. +7].
#define WS_NEED 266240

// async global->LDS, 16B per lane; LDS dest is wave-uniform base + lane*16
// (per-thread dest expression base+tid*16 is the R4-verified pattern)
__device__ __forceinline__ void gload_lds16(const void* g, void* l) {
    __builtin_amdgcn_global_load_lds(
        (const __attribute__((address_space(1))) unsigned int*)g,
        (__attribute__((address_space(3))) unsigned int*)l, 16, 0, 0);
}

// ============================ fast path ====================================
__global__ __launch_bounds__(256) void prep_kernel(
    const float* __restrict__ embed,
    _Float16* __restrict__ planes,
    float* __restrict__ e2g,
    float* __restrict__ counts,        // out_avg region  (zeroed here)
    float* __restrict__ distsum)       // out_commit slot (zeroed here)
{
    const int gidx = blockIdx.x * 256 + threadIdx.x;   // 8192 threads
    const int g  = gidx >> 7;
    const int k  = (gidx >> 6) & 1;
    const int l  = gidx & 63;
    const int q  = l >> 4;
    const int ln = l & 15;
    const int c  = g * 16 + ln;
    const int jb = k * 32 + q * 8;

    const float4 v0 = *(const float4*)(embed + (size_t)c * DIM + jb);
    const float4 v1 = *(const float4*)(embed + (size_t)c * DIM + jb + 4);
    const float xf[8] = {v0.x, v0.y, v0.z, v0.w, v1.x, v1.y, v1.z, v1.w};
    f16x8 h1, h2;
    #pragma unroll
    for (int e = 0; e < 8; ++e) {
        const _Float16 a = (_Float16)xf[e];
        h1[e] = a;
        h2[e] = (_Float16)(xf[e] - (float)a);   // exact residual
    }
    const int off = ((g * 2 + k) * 64 + l) * 8;
    *(f16x8*)(planes + off)         = h1;
    *(f16x8*)(planes + 65536 + off) = h2;

    if (gidx < KE) {
        const float4* rp = (const float4*)(embed + (size_t)gidx * DIM);
        float s = 0.f;
        #pragma unroll
        for (int i = 0; i < 16; ++i) {
            const float4 v = rp[i];
            s += v.x * v.x + v.y * v.y + v.z * v.z + v.w * v.w;
        }
        e2g[gidx]    = s;
        counts[gidx] = 0.f;
        if (gidx == 0) distsum[0] = 0.f;
    }
}

// Fused argmin + gather; K split ACROSS the 4 waves of a block.
// Model (R0-R4): per-CU MFMA work is fixed; per-CU B traffic = 4MB/m
// (m = 16-row tiles per wave). R0 (m=2, 16 waves/CU, no barriers): 46us,
// delivery ~= MFMA time. R3 (m=4) starved at 4 waves/CU; R4's barriers
// re-exposed latency. This version: block = 64 t, wave w = codes
// [256w,256w+256) with m=4 -> traffic/CU = 1MB (7.8us), grid 1024 = 4
// blocks/CU (12-16 waves/CU), NO hot-loop barriers, intra-block K-reduce
// keeps the fused no-keys epilogue. x staged once per block via LDS.
// Numerics: drop the x_lo*e_lo MFMA (~1e-6 abs, vs absmax 0.00195) ->
// 6 MFMAs/tile, small-terms-first order kept, strict < + ascending ties.
__global__ __launch_bounds__(256, 3) void argmin_fused(
    const float* __restrict__ x,       // [B][D][T]
    const _Float16* __restrict__ P,    // ws planes (hi at +0, lo at +131072 B)
    const float* __restrict__ e2g,     // ws e2
    const float* __restrict__ embed,
    float* __restrict__ out_q,
    float* __restrict__ out_idx,
    float* __restrict__ counts,
    float* __restrict__ distsum)
{
    __shared__ __align__(16) float x_lds[4096];   // [j][t'] 64x64 f32 (16 KB)
    __shared__ float e2s[1024];
    __shared__ float rs[4][64];                   // per-wave candidates
    __shared__ int   ri[4][64];
    __shared__ float x2s[64];
    __shared__ int   ibest[64];

    const int tid = threadIdx.x;
    const int l   = tid & 63;
    const int w   = tid >> 6;          // w = K-quarter index
    const int q   = l >> 4;
    const int ln  = l & 15;
    const int n0  = blockIdx.x << 6;   // 64 t per block
    const int b   = n0 >> 11;          // TT = 2048
    const int t0  = n0 & 2047;

    // ---- stage x[j=0..63][t0..t0+63] into LDS (linear dest, R4 pattern) ---
    {
        const float* xb = x + (size_t)b * DIM * TT + t0;
        #pragma unroll
        for (int r = 0; r < 4; ++r) {
            const int idx = r * 256 + tid;         // 1024 x 16B = 16 KB
            gload_lds16(xb + (size_t)(idx >> 4) * TT + (idx & 15) * 4,
                        (char*)x_lds + idx * 16);
        }
    }
    *(float4*)&e2s[tid * 4] = *(const float4*)(e2g + tid * 4);
    __syncthreads();                   // drains x DMA + e2s writes

    // ---- A fragments from LDS: fp16 split (layout verified R5/R6) ----
    // t = t0 + m*16 + ln, j = k*32 + q*8 + jj  (all 4 waves build same A)
    f16x8 af[2][4][2];                 // [plane][m][k] = 64 VGPRs
    float x2p[4] = {0.f, 0.f, 0.f, 0.f};
    #pragma unroll
    for (int m = 0; m < 4; ++m)
        #pragma unroll
        for (int k = 0; k < 2; ++k)
            #pragma unroll
            for (int jj = 0; jj < 8; ++jj) {
                const float xf = x_lds[(k * 32 + q * 8 + jj) * 64 + m * 16 + ln];
                const _Float16 h1 = (_Float16)xf;
                af[0][m][k][jj] = h1;
                af[1][m][k][jj] = (_Float16)(xf - (float)h1);
                x2p[m] = fmaf(xf, xf, x2p[m]);
            }
    #pragma unroll
    for (int m = 0; m < 4; ++m) {
        x2p[m] += __shfl_xor(x2p[m], 16);
        x2p[m] += __shfl_xor(x2p[m], 32);
        if (w == 0 && q == 0) x2s[m * 16 + ln] = x2p[m];
    }

    float bs[4][4];
    int   bi_[4][4];
    #pragma unroll
    for (int m = 0; m < 4; ++m)
        #pragma unroll
        for (int r = 0; r < 4; ++r) { bs[m][r] = FLT_MAX; bi_[m][r] = 0; }

    // B fragments for group gg (f16x8 view, verified R0 indexing):
    //   buf[0]=hi,k0  buf[1]=hi,k1  buf[2]=lo,k0  buf[3]=lo,k1
    // Overfetch at gg=64 (w=3 prefetch tail) lands in lo plane/e2: harmless.
    const f16x8* base = (const f16x8*)P + l;
#define LOADG(buf, gg) do {                                                  \
        const f16x8* gp_ = base + (gg) * 128;                                \
        buf[0] = gp_[0];                                                     \
        buf[1] = gp_[64];                                                    \
        buf[2] = gp_[8192];                                                  \
        buf[3] = gp_[8192 + 64];                                             \
    } while (0)

    // 6 MFMAs per (group,m): lo*hi, hi*lo, hi*hi (small terms first).
#define COMPUTE(buf, gg) do {                                                \
        const int   cgl_ = (gg) * 16 + ln;                                   \
        const float e2c_ = e2s[cgl_];                                        \
        _Pragma("unroll")                                                    \
        for (int m = 0; m < 4; ++m) {                                        \
            f32x4 C = {0.f, 0.f, 0.f, 0.f};                                  \
            C = __builtin_amdgcn_mfma_f32_16x16x32_f16(af[1][m][0], buf[0], C, 0, 0, 0); \
            C = __builtin_amdgcn_mfma_f32_16x16x32_f16(af[1][m][1], buf[1], C, 0, 0, 0); \
            C = __builtin_amdgcn_mfma_f32_16x16x32_f16(af[0][m][0], buf[2], C, 0, 0, 0); \
            C = __builtin_amdgcn_mfma_f32_16x16x32_f16(af[0][m][1], buf[3], C, 0, 0, 0); \
            C = __builtin_amdgcn_mfma_f32_16x16x32_f16(af[0][m][0], buf[0], C, 0, 0, 0); \
            C = __builtin_amdgcn_mfma_f32_16x16x32_f16(af[0][m][1], buf[1], C, 0, 0, 0); \
            _Pragma("unroll")                                                \
            for (int r = 0; r < 4; ++r) {                                    \
                const float s = fmaf(-2.f, C[r], e2c_);                      \
                /* strict < + ascending c keeps lowest index on ties */      \
                if (s < bs[m][r]) { bs[m][r] = s; bi_[m][r] = cgl_; }        \
            }                                                                \
        }                                                                    \
    } while (0)

    // ---- hot loop: this wave's 16 groups (256 codes), dbuf distance-1 ----
    const int gbase = w * 16;
    f16x8 B0[4], B1[4];
    LOADG(B0, gbase);
    #pragma unroll 1
    for (int gl = 0; gl < 16; gl += 2) {
        LOADG(B1, gbase + gl + 1);
        COMPUTE(B0, gbase + gl);
        LOADG(B0, gbase + gl + 2);     // tail gg=64: harmless overfetch
        COMPUTE(B1, gbase + gl + 1);
    }
#undef LOADG
#undef COMPUTE

    // ---- per-wave reduce over 16 code-columns -> LDS candidates ----
    #pragma unroll
    for (int m = 0; m < 4; ++m)
        #pragma unroll
        for (int r = 0; r < 4; ++r) {
            float s = bs[m][r]; int i = bi_[m][r];
            #pragma unroll
            for (int mask = 1; mask < 16; mask <<= 1) {
                const float s2 = __shfl_xor(s, mask);
                const int   i2 = __shfl_xor(i, mask);
                if (s2 < s || (s2 == s && i2 < i)) { s = s2; i = i2; }
            }
            if (ln == 0) {
                const int t_loc = m * 16 + q * 4 + r;   // C-row map (verified)
                rs[w][t_loc] = s;
                ri[w][t_loc] = i;
            }
        }
    __syncthreads();

    // ---- cross-wave K-reduce (w ascending = index ascending: strict <) ----
    if (tid < 64) {
        float s = rs[0][tid]; int i = ri[0][tid];
        #pragma unroll
        for (int ww = 1; ww < 4; ++ww) {
            const float s2 = rs[ww][tid];
            const int   i2 = ri[ww][tid];
            if (s2 < s) { s = s2; i = i2; }
        }
        ibest[tid] = i;
        out_idx[n0 + tid] = (float)i;
        atomicAdd(&counts[i], 1.0f);
        float md = x2s[tid] + s;           // ||x||^2 + e^2 - 2 x.e
        #pragma unroll
        for (int off = 1; off < 64; off <<= 1) md += __shfl_xor(md, off);
        if (tid == 0) atomicAdd(distsum, md);
    }
    __syncthreads();

    // ---- gather: out_q[b][j][t0+tt] = embed[ibest[tt]][j] (embed L2-hot) ---
    #pragma unroll
    for (int p = 0; p < 16; ++p) {
        const int f  = p * 256 + tid;
        const int j  = f >> 6;
        const int tt = f & 63;
        out_q[(size_t)(b * DIM + j) * TT + t0 + tt] =
            embed[(size_t)ibest[tt] * DIM + j];
    }
}

// ======================= fallback path (Round-5, passed) ====================
#define EP_ROW   72
#define EP_PLANE 4608
#define SMEM_BYTES (36864 + 4096 + 512 + 512 + 16)

__global__ __launch_bounds__(256, 2) void argmin_fb(
    const float* __restrict__ x, const float* __restrict__ embed,
    float* __restrict__ out_q, float* __restrict__ out_idx,
    float* __restrict__ counts, float* __restrict__ distsum)
{
    __shared__ __align__(16) char smem[SMEM_BYTES];
    _Float16* ep  = (_Float16*)smem;
    float* e2s    = (float*)(smem + 36864);
    float* x2s    = (float*)(smem + 36864 + 4096);
    int*   ibest  = (int*)  (smem + 36864 + 4608);
    float* mdsum  = (float*)(smem + 36864 + 5120);

    const int tid = threadIdx.x;
    const int l   = tid & 63;
    const int w   = tid >> 6;
    const int q   = l >> 4;
    const int ln  = l & 15;
    const int bid = blockIdx.x;
    const int b   = bid >> 4;
    const int t0  = (bid & 15) << 7;

    if (tid == 0) mdsum[0] = 0.f;
    #pragma unroll
    for (int pass = 0; pass < 4; ++pass) {
        const int c = pass * 256 + tid;
        const float4* rp = (const float4*)(embed + (size_t)c * DIM);
        float s = 0.f;
        #pragma unroll
        for (int i = 0; i < 16; ++i) {
            const float4 v = rp[i];
            s += v.x * v.x + v.y * v.y + v.z * v.z + v.w * v.w;
        }
        e2s[c] = s;
    }
    f16x8 af[2][2][2];
    float x2p[2] = {0.f, 0.f};
    #pragma unroll
    for (int m = 0; m < 2; ++m)
        #pragma unroll
        for (int k = 0; k < 2; ++k)
            #pragma unroll
            for (int jj = 0; jj < 8; ++jj) {
                const int j = k * 32 + q * 8 + jj;
                const float xf = x[(size_t)(b * DIM + j) * TT + t0 + w * 32 + m * 16 + ln];
                const _Float16 h1 = (_Float16)xf;
                af[0][m][k][jj] = h1;
                af[1][m][k][jj] = (_Float16)(xf - (float)h1);
                x2p[m] = fmaf(xf, xf, x2p[m]);
            }
    #pragma unroll
    for (int m = 0; m < 2; ++m) {
        x2p[m] += __shfl_xor(x2p[m], 16);
        x2p[m] += __shfl_xor(x2p[m], 32);
    }
    if (q == 0) { x2s[w * 32 + ln] = x2p[0]; x2s[w * 32 + 16 + ln] = x2p[1]; }
    {
        #pragma unroll
        for (int pass = 0; pass < 4; ++pass) {
            const int c_loc = (tid >> 4) + pass * 16;
            const int j4    = (tid & 15) * 4;
            const float4 v = *(const float4*)(embed + (size_t)c_loc * DIM + j4);
            f16x4 h1, h2;
            h1[0] = (_Float16)v.x; h2[0] = (_Float16)(v.x - (float)h1[0]);
            h1[1] = (_Float16)v.y; h2[1] = (_Float16)(v.y - (float)h1[1]);
            h1[2] = (_Float16)v.z; h2[2] = (_Float16)(v.z - (float)h1[2]);
            h1[3] = (_Float16)v.w; h2[3] = (_Float16)(v.w - (float)h1[3]);
            *(f16x4*)(ep + c_loc * EP_ROW + j4)            = h1;
            *(f16x4*)(ep + EP_PLANE + c_loc * EP_ROW + j4) = h2;
        }
    }
    __syncthreads();
    float bs[2][4]; int bi[2][4];
    #pragma unroll
    for (int m = 0; m < 2; ++m)
        #pragma unroll
        for (int r = 0; r < 4; ++r) { bs[m][r] = FLT_MAX; bi[m][r] = 0; }
    for (int kc = 0; kc < 16; ++kc) {
        const int cur = kc & 1, nxt = cur ^ 1;
        float4 ev[4];
        if (kc < 15)
            #pragma unroll
            for (int pass = 0; pass < 4; ++pass) {
                const int c_loc = (tid >> 4) + pass * 16;
                const int j4    = (tid & 15) * 4;
                ev[pass] = *(const float4*)(embed + (size_t)((kc + 1) * 64 + c_loc) * DIM + j4);
            }
        const _Float16* p1 = ep + cur * 2 * EP_PLANE;
        const _Float16* p2 = p1 + EP_PLANE;
        #pragma unroll
        for (int n = 0; n < 4; ++n) {
            const int coff = (n * 16 + ln) * EP_ROW + q * 8;
            const f16x8 b1k0 = *(const f16x8*)(p1 + coff);
            const f16x8 b1k1 = *(const f16x8*)(p1 + coff + 32);
            const f16x8 b2k0 = *(const f16x8*)(p2 + coff);
            const f16x8 b2k1 = *(const f16x8*)(p2 + coff + 32);
            const int   c_lane = kc * 64 + n * 16 + ln;
            const float e2c    = e2s[c_lane];
            #pragma unroll
            for (int m = 0; m < 2; ++m) {
                f32x4 C = {0.f, 0.f, 0.f, 0.f};
                C = __builtin_amdgcn_mfma_f32_16x16x32_f16(af[1][m][0], b2k0, C, 0, 0, 0);
                C = __builtin_amdgcn_mfma_f32_16x16x32_f16(af[1][m][1], b2k1, C, 0, 0, 0);
                C = __builtin_amdgcn_mfma_f32_16x16x32_f16(af[1][m][0], b1k0, C, 0, 0, 0);
                C = __builtin_amdgcn_mfma_f32_16x16x32_f16(af[1][m][1], b1k1, C, 0, 0, 0);
                C = __builtin_amdgcn_mfma_f32_16x16x32_f16(af[0][m][0], b2k0, C, 0, 0, 0);
                C = __builtin_amdgcn_mfma_f32_16x16x32_f16(af[0][m][1], b2k1, C, 0, 0, 0);
                C = __builtin_amdgcn_mfma_f32_16x16x32_f16(af[0][m][0], b1k0, C, 0, 0, 0);
                C = __builtin_amdgcn_mfma_f32_16x16x32_f16(af[0][m][1], b1k1, C, 0, 0, 0);
                #pragma unroll
                for (int r = 0; r < 4; ++r) {
                    const float s = fmaf(-2.f, C[r], e2c);
                    if (s < bs[m][r]) { bs[m][r] = s; bi[m][r] = c_lane; }
                }
            }
        }
        if (kc < 15) {
            _Float16* w1 = ep + nxt * 2 * EP_PLANE;
            _Float16* w2 = w1 + EP_PLANE;
            #pragma unroll
            for (int pass = 0; pass < 4; ++pass) {
                const int c_loc = (tid >> 4) + pass * 16;
                const int j4    = (tid & 15) * 4;
                const float4 v = ev[pass];
                f16x4 h1, h2;
                h1[0] = (_Float16)v.x; h2[0] = (_Float16)(v.x - (float)h1[0]);
                h1[1] = (_Float16)v.y; h2[1] = (_Float16)(v.y - (float)h1[1]);
                h1[2] = (_Float16)v.z; h2[2] = (_Float16)(v.z - (float)h1[2]);
                h1[3] = (_Float16)v.w; h2[3] = (_Float16)(v.w - (float)h1[3]);
                *(f16x4*)(w1 + c_loc * EP_ROW + j4) = h1;
                *(f16x4*)(w2 + c_loc * EP_ROW + j4) = h2;
            }
        }
        __syncthreads();
    }
    float mdloc = 0.f;
    #pragma unroll
    for (int m = 0; m < 2; ++m)
        #pragma unroll
        for (int r = 0; r < 4; ++r) {
            float s = bs[m][r]; int i = bi[m][r];
            #pragma unroll
            for (int mask = 1; mask < 16; mask <<= 1) {
                const float s2 = __shfl_xor(s, mask);
                const int   i2 = __shfl_xor(i, mask);
                if (s2 < s || (s2 == s && i2 < i)) { s = s2; i = i2; }
            }
            if (ln == 0) {
                const int t_loc = w * 32 + m * 16 + q * 4 + r;
                ibest[t_loc] = i;
                out_idx[b * TT + t0 + t_loc] = (float)i;
                atomicAdd(&counts[i], 1.0f);
                mdloc += x2s[t_loc] + s;
            }
        }
    if (ln == 0) atomicAdd(mdsum, mdloc);
    __syncthreads();
    if (tid == 0) atomicAdd(distsum, mdsum[0]);
    #pragma unroll
    for (int p = 0; p < 32; ++p) {
        const int f  = p * 256 + tid;
        const int j  = f >> 7;
        const int tt = f & 127;
        out_q[(size_t)(b * DIM + j) * TT + t0 + tt] =
            embed[(size_t)ibest[tt] * DIM + j];
    }
}

// finalize: in-place counts->avg_probs, perplexity, usage, commitment
__global__ __launch_bounds__(1024) void finalize_kernel(
    float* __restrict__ avg, float* __restrict__ commit_slot,
    float* __restrict__ out_perp, float* __restrict__ out_usage)
{
    __shared__ float s_ent[1024];
    __shared__ float s_use[1024];
    const int k = threadIdx.x;
    const float p = avg[k] * (1.0f / (float)NTOT);
    avg[k] = p;
    s_ent[k] = p * logf(p + 1e-10f);
    s_use[k] = p * logf(p * 1024.f + 1e-10f);
    __syncthreads();
    for (int off = 512; off > 0; off >>= 1) {
        if (k < off) { s_ent[k] += s_ent[k + off]; s_use[k] += s_use[k + off]; }
        __syncthreads();
    }
    if (k == 0) {
        const float ds = commit_slot[0];
        *out_perp      = expf(-s_ent[0]);
        *out_usage     = s_use[0];
        commit_slot[0] = 0.25f * ds * (1.0f / ((float)NTOT * (float)DIM));
    }
}

extern "C" void kernel_launch(void* const* d_in, const int* in_sizes, int n_in,
                              void* d_out, int out_size, void* d_ws, size_t ws_size,
                              hipStream_t stream) {
    const float* x     = (const float*)d_in[0];
    const float* embed = (const float*)d_in[1];

    float* out        = (float*)d_out;
    float* out_q      = out;             // 4194304
    float* out_commit = out + 4194304;   // distsum accumulator first
    float* out_perp   = out + 4194305;
    float* out_avg    = out + 4194306;   // counts accumulator first
    float* out_idx    = out + 4195330;
    // usage at out + 4260866

    if (ws_size >= WS_NEED) {
        _Float16* planes = (_Float16*)d_ws;
        float*    e2g    = (float*)((char*)d_ws + 262144);
        prep_kernel<<<32, 256, 0, stream>>>(embed, planes, e2g, out_avg, out_commit);
        argmin_fused<<<1024, 256, 0, stream>>>(x, planes, e2g, embed,
                                               out_q, out_idx, out_avg, out_commit);
    } else {
        hipMemsetAsync(out_commit, 0, 1026 * sizeof(float), stream);
        argmin_fb<<<512, 256, 0, stream>>>(x, embed, out_q, out_idx, out_avg, out_commit);
    }
    finalize_kernel<<<1, 1024, 0, stream>>>(out_avg, out_commit, out_perp, out + 4260866);
}

// Round 6
// 124.824 us; speedup vs baseline: 1.2447x; 1.0688x over previous
//
#include <hip/hip_runtime.h>
#include <cfloat>
#include <cmath>

#define DIM 64
#define TT 2048
#define NTOT 65536
#define KE 1024

typedef _Float16 f16x8 __attribute__((ext_vector_type(8)));
typedef _Float16 f16x4 __attribute__((ext_vector_type(4)));
typedef float    f32x4 __attribute__((ext_vector_type(4)));

// ws layout (bytes):
//   planes [0, 262144)      : fp16 hi plane (131072 B) + fp16 lo plane (131072 B)
//   e2     [262144, 266240) : 1024 f32
// plane vector layout (B-fragment-ready, verified R5/R6): f16x8 index
//   ((g*2+k)*64 + l) for group g (16 codes), kstep k, lane l=q*16+ln holding
//   embed_plane[c=g*16+ln][j=k*32+q*8 .. +7].
#define WS_NEED 266240

// ============================ fast path ====================================
__global__ __launch_bounds__(256) void prep_kernel(
    const float* __restrict__ embed,
    _Float16* __restrict__ planes,
    float* __restrict__ e2g,
    float* __restrict__ counts,        // out_avg region  (zeroed here)
    float* __restrict__ distsum)       // out_commit slot (zeroed here)
{
    const int gidx = blockIdx.x * 256 + threadIdx.x;   // 8192 threads
    const int g  = gidx >> 7;
    const int k  = (gidx >> 6) & 1;
    const int l  = gidx & 63;
    const int q  = l >> 4;
    const int ln = l & 15;
    const int c  = g * 16 + ln;
    const int jb = k * 32 + q * 8;

    const float4 v0 = *(const float4*)(embed + (size_t)c * DIM + jb);
    const float4 v1 = *(const float4*)(embed + (size_t)c * DIM + jb + 4);
    const float xf[8] = {v0.x, v0.y, v0.z, v0.w, v1.x, v1.y, v1.z, v1.w};
    f16x8 h1, h2;
    #pragma unroll
    for (int e = 0; e < 8; ++e) {
        const _Float16 a = (_Float16)xf[e];
        h1[e] = a;
        h2[e] = (_Float16)(xf[e] - (float)a);   // exact residual
    }
    const int off = ((g * 2 + k) * 64 + l) * 8;
    *(f16x8*)(planes + off)         = h1;
    *(f16x8*)(planes + 65536 + off) = h2;

    if (gidx < KE) {
        const float4* rp = (const float4*)(embed + (size_t)gidx * DIM);
        float s = 0.f;
        #pragma unroll
        for (int i = 0; i < 16; ++i) {
            const float4 v = rp[i];
            s += v.x * v.x + v.y * v.y + v.z * v.z + v.w * v.w;
        }
        e2g[gidx]    = s;
        counts[gidx] = 0.f;
        if (gidx == 0) distsum[0] = 0.f;
    }
}

// Fused argmin + gather built around R0's PROVEN 46us hot loop.
// R1-R5 post-mortem: every restructuring (LDS staging, register pipelines,
// m=4, chunked windows, wave-K-split with x staging) landed at 78-89us; only
// R0's codegen (m=2, 32-group plain loop, direct global loads, no hot-loop
// barriers, compiler-scheduled prefetch) measured 46us. So: keep that loop
// BYTE-COMPATIBLE and change only what's independently verified:
//  (a) 8-wave / 512-thread block covering 128 t and BOTH K-halves
//      (waves 0-3: kq=0, waves 4-7: kq=1) -> block-local argmin, fused
//      gather/counts/distsum epilogue, no keys pass (verified R1/R5).
//  (b) 6 MFMAs per tile instead of 8 (drop x_lo*e_lo; verified R5,
//      absmax unchanged 0.001953125).
// Per-wave profile identical to R0: 32 iters x {4x16B loads + 12 MFMAs}.
// Grid 512 x 512thr = 2 blocks/CU = 16 waves/CU, same as R0.
__global__ __launch_bounds__(512, 4) void argmin_fused(
    const float* __restrict__ x,       // [B][D][T]
    const f16x8* __restrict__ P,       // ws planes (hi at +0, lo at +131072 B)
    const float* __restrict__ e2g,     // ws e2
    const float* __restrict__ embed,
    float* __restrict__ out_q,
    float* __restrict__ out_idx,
    float* __restrict__ counts,
    float* __restrict__ distsum)
{
    __shared__ float e2s[1024];
    __shared__ float rs[2][128];       // per-K-half candidates
    __shared__ int   ri[2][128];
    __shared__ float x2s[128];
    __shared__ int   ibest[128];

    const int tid = threadIdx.x;       // 0..511
    const int l   = tid & 63;
    const int w   = tid >> 6;          // 0..7
    const int wq  = w & 3;             // t-quarter within block
    const int kq  = w >> 2;            // K-half
    const int q   = l >> 4;
    const int ln  = l & 15;
    const int bid = blockIdx.x;        // 512 blocks = 32 b x 16 t-tiles
    const int b   = bid >> 4;
    const int t0  = (bid & 15) << 7;   // 128 t per block

    if (tid < 256)
        *(float4*)&e2s[tid * 4] = *(const float4*)(e2g + tid * 4);

    // ---- A fragments: fp16 split in registers (layout verified R5/R6) ----
    // t = t0 + wq*32 + m*16 + ln, j = k*32 + q*8 + jj
    f16x8 af[2][2][2];                 // [plane][m][k]
    float x2p[2] = {0.f, 0.f};
    #pragma unroll
    for (int m = 0; m < 2; ++m)
        #pragma unroll
        for (int k = 0; k < 2; ++k)
            #pragma unroll
            for (int jj = 0; jj < 8; ++jj) {
                const int j = k * 32 + q * 8 + jj;
                const float xf = x[(size_t)(b * DIM + j) * TT + t0 + wq * 32 + m * 16 + ln];
                const _Float16 h1 = (_Float16)xf;
                af[0][m][k][jj] = h1;
                af[1][m][k][jj] = (_Float16)(xf - (float)h1);
                x2p[m] = fmaf(xf, xf, x2p[m]);
            }
    // full ||x_t||^2: sum the 4 q-quarters (lanes with same ln)
    #pragma unroll
    for (int m = 0; m < 2; ++m) {
        x2p[m] += __shfl_xor(x2p[m], 16);
        x2p[m] += __shfl_xor(x2p[m], 32);
    }
    if (kq == 0 && q == 0) {
        x2s[wq * 32 + ln]      = x2p[0];
        x2s[wq * 32 + 16 + ln] = x2p[1];
    }
    __syncthreads();                   // e2s, x2s ready (only pre-loop barrier)

    float bs[2][4];
    int   bi_[2][4];
    #pragma unroll
    for (int m = 0; m < 2; ++m)
        #pragma unroll
        for (int r = 0; r < 4; ++r) { bs[m][r] = FLT_MAX; bi_[m][r] = 0; }

    // ---- hot loop: 32 groups of 16 codes from this wave's K-half ----
    // (R0-verbatim structure: plain loop, direct loads, compiler-scheduled)
    const f16x8* base = P + l + kq * 4096;
    for (int gl = 0; gl < 32; ++gl) {
        const f16x8* gp = base + gl * 128;
        const f16x8 b1k0 = gp[0];              // hi plane, k0
        const f16x8 b1k1 = gp[64];             // hi plane, k1
        const f16x8 b2k0 = gp[8192];           // lo plane, k0
        const f16x8 b2k1 = gp[8192 + 64];      // lo plane, k1
        const int   cl   = gl * 16 + ln;
        const int   cgl  = kq * 512 + cl;
        const float e2c  = e2s[cgl];
        #pragma unroll
        for (int m = 0; m < 2; ++m) {
            f32x4 C = {0.f, 0.f, 0.f, 0.f};
            // 6-MFMA split (verified R5): lo*hi, hi*lo, hi*hi, small first
            C = __builtin_amdgcn_mfma_f32_16x16x32_f16(af[1][m][0], b1k0, C, 0, 0, 0);
            C = __builtin_amdgcn_mfma_f32_16x16x32_f16(af[1][m][1], b1k1, C, 0, 0, 0);
            C = __builtin_amdgcn_mfma_f32_16x16x32_f16(af[0][m][0], b2k0, C, 0, 0, 0);
            C = __builtin_amdgcn_mfma_f32_16x16x32_f16(af[0][m][1], b2k1, C, 0, 0, 0);
            C = __builtin_amdgcn_mfma_f32_16x16x32_f16(af[0][m][0], b1k0, C, 0, 0, 0);
            C = __builtin_amdgcn_mfma_f32_16x16x32_f16(af[0][m][1], b1k1, C, 0, 0, 0);
            #pragma unroll
            for (int r = 0; r < 4; ++r) {
                const float s = fmaf(-2.f, C[r], e2c);
                // strict < + ascending c keeps lowest index on ties
                if (s < bs[m][r]) { bs[m][r] = s; bi_[m][r] = cgl; }
            }
        }
    }

    // ---- per-wave reduce over the 16 code-columns -> LDS candidates ----
    #pragma unroll
    for (int m = 0; m < 2; ++m)
        #pragma unroll
        for (int r = 0; r < 4; ++r) {
            float s = bs[m][r]; int i = bi_[m][r];
            #pragma unroll
            for (int mask = 1; mask < 16; mask <<= 1) {
                const float s2 = __shfl_xor(s, mask);
                const int   i2 = __shfl_xor(i, mask);
                if (s2 < s || (s2 == s && i2 < i)) { s = s2; i = i2; }
            }
            if (ln == 0) {
                const int t_loc = wq * 32 + m * 16 + q * 4 + r;  // C-row map
                rs[kq][t_loc] = s;
                ri[kq][t_loc] = i;
            }
        }
    __syncthreads();

    // ---- cross-K-half reduce; kq0 indices < kq1: strict < keeps ties ----
    if (tid < 128) {
        float s = rs[0][tid]; int i = ri[0][tid];
        const float s1 = rs[1][tid];
        if (s1 < s) { s = s1; i = ri[1][tid]; }
        ibest[tid] = i;
        out_idx[bid * 128 + tid] = (float)i;     // == b*TT + t0 + tid
        atomicAdd(&counts[i], 1.0f);
        float md = x2s[tid] + s;                 // ||x||^2 + e^2 - 2 x.e
        #pragma unroll
        for (int off = 1; off < 64; off <<= 1) md += __shfl_xor(md, off);
        if (l == 0) atomicAdd(distsum, md);      // 2 atomics per block
    }
    __syncthreads();

    // ---- gather: out_q[b][j][t0+tt] = embed[ibest[tt]][j] (embed L2-hot) ---
    #pragma unroll
    for (int p = 0; p < 16; ++p) {
        const int f  = p * 512 + tid;
        const int j  = f >> 7;
        const int tt = f & 127;
        out_q[(size_t)(b * DIM + j) * TT + t0 + tt] =
            embed[(size_t)ibest[tt] * DIM + j];
    }
}

// ======================= fallback path (Round-5, passed) ====================
#define EP_ROW   72
#define EP_PLANE 4608
#define SMEM_BYTES (36864 + 4096 + 512 + 512 + 16)

__global__ __launch_bounds__(256, 2) void argmin_fb(
    const float* __restrict__ x, const float* __restrict__ embed,
    float* __restrict__ out_q, float* __restrict__ out_idx,
    float* __restrict__ counts, float* __restrict__ distsum)
{
    __shared__ __align__(16) char smem[SMEM_BYTES];
    _Float16* ep  = (_Float16*)smem;
    float* e2s    = (float*)(smem + 36864);
    float* x2s    = (float*)(smem + 36864 + 4096);
    int*   ibest  = (int*)  (smem + 36864 + 4608);
    float* mdsum  = (float*)(smem + 36864 + 5120);

    const int tid = threadIdx.x;
    const int l   = tid & 63;
    const int w   = tid >> 6;
    const int q   = l >> 4;
    const int ln  = l & 15;
    const int bid = blockIdx.x;
    const int b   = bid >> 4;
    const int t0  = (bid & 15) << 7;

    if (tid == 0) mdsum[0] = 0.f;
    #pragma unroll
    for (int pass = 0; pass < 4; ++pass) {
        const int c = pass * 256 + tid;
        const float4* rp = (const float4*)(embed + (size_t)c * DIM);
        float s = 0.f;
        #pragma unroll
        for (int i = 0; i < 16; ++i) {
            const float4 v = rp[i];
            s += v.x * v.x + v.y * v.y + v.z * v.z + v.w * v.w;
        }
        e2s[c] = s;
    }
    f16x8 af[2][2][2];
    float x2p[2] = {0.f, 0.f};
    #pragma unroll
    for (int m = 0; m < 2; ++m)
        #pragma unroll
        for (int k = 0; k < 2; ++k)
            #pragma unroll
            for (int jj = 0; jj < 8; ++jj) {
                const int j = k * 32 + q * 8 + jj;
                const float xf = x[(size_t)(b * DIM + j) * TT + t0 + w * 32 + m * 16 + ln];
                const _Float16 h1 = (_Float16)xf;
                af[0][m][k][jj] = h1;
                af[1][m][k][jj] = (_Float16)(xf - (float)h1);
                x2p[m] = fmaf(xf, xf, x2p[m]);
            }
    #pragma unroll
    for (int m = 0; m < 2; ++m) {
        x2p[m] += __shfl_xor(x2p[m], 16);
        x2p[m] += __shfl_xor(x2p[m], 32);
    }
    if (q == 0) { x2s[w * 32 + ln] = x2p[0]; x2s[w * 32 + 16 + ln] = x2p[1]; }
    {
        #pragma unroll
        for (int pass = 0; pass < 4; ++pass) {
            const int c_loc = (tid >> 4) + pass * 16;
            const int j4    = (tid & 15) * 4;
            const float4 v = *(const float4*)(embed + (size_t)c_loc * DIM + j4);
            f16x4 h1, h2;
            h1[0] = (_Float16)v.x; h2[0] = (_Float16)(v.x - (float)h1[0]);
            h1[1] = (_Float16)v.y; h2[1] = (_Float16)(v.y - (float)h1[1]);
            h1[2] = (_Float16)v.z; h2[2] = (_Float16)(v.z - (float)h1[2]);
            h1[3] = (_Float16)v.w; h2[3] = (_Float16)(v.w - (float)h1[3]);
            *(f16x4*)(ep + c_loc * EP_ROW + j4)            = h1;
            *(f16x4*)(ep + EP_PLANE + c_loc * EP_ROW + j4) = h2;
        }
    }
    __syncthreads();
    float bs[2][4]; int bi[2][4];
    #pragma unroll
    for (int m = 0; m < 2; ++m)
        #pragma unroll
        for (int r = 0; r < 4; ++r) { bs[m][r] = FLT_MAX; bi[m][r] = 0; }
    for (int kc = 0; kc < 16; ++kc) {
        const int cur = kc & 1, nxt = cur ^ 1;
        float4 ev[4];
        if (kc < 15)
            #pragma unroll
            for (int pass = 0; pass < 4; ++pass) {
                const int c_loc = (tid >> 4) + pass * 16;
                const int j4    = (tid & 15) * 4;
                ev[pass] = *(const float4*)(embed + (size_t)((kc + 1) * 64 + c_loc) * DIM + j4);
            }
        const _Float16* p1 = ep + cur * 2 * EP_PLANE;
        const _Float16* p2 = p1 + EP_PLANE;
        #pragma unroll
        for (int n = 0; n < 4; ++n) {
            const int coff = (n * 16 + ln) * EP_ROW + q * 8;
            const f16x8 b1k0 = *(const f16x8*)(p1 + coff);
            const f16x8 b1k1 = *(const f16x8*)(p1 + coff + 32);
            const f16x8 b2k0 = *(const f16x8*)(p2 + coff);
            const f16x8 b2k1 = *(const f16x8*)(p2 + coff + 32);
            const int   c_lane = kc * 64 + n * 16 + ln;
            const float e2c    = e2s[c_lane];
            #pragma unroll
            for (int m = 0; m < 2; ++m) {
                f32x4 C = {0.f, 0.f, 0.f, 0.f};
                C = __builtin_amdgcn_mfma_f32_16x16x32_f16(af[1][m][0], b2k0, C, 0, 0, 0);
                C = __builtin_amdgcn_mfma_f32_16x16x32_f16(af[1][m][1], b2k1, C, 0, 0, 0);
                C = __builtin_amdgcn_mfma_f32_16x16x32_f16(af[1][m][0], b1k0, C, 0, 0, 0);
                C = __builtin_amdgcn_mfma_f32_16x16x32_f16(af[1][m][1], b1k1, C, 0, 0, 0);
                C = __builtin_amdgcn_mfma_f32_16x16x32_f16(af[0][m][0], b2k0, C, 0, 0, 0);
                C = __builtin_amdgcn_mfma_f32_16x16x32_f16(af[0][m][1], b2k1, C, 0, 0, 0);
                C = __builtin_amdgcn_mfma_f32_16x16x32_f16(af[0][m][0], b1k0, C, 0, 0, 0);
                C = __builtin_amdgcn_mfma_f32_16x16x32_f16(af[0][m][1], b1k1, C, 0, 0, 0);
                #pragma unroll
                for (int r = 0; r < 4; ++r) {
                    const float s = fmaf(-2.f, C[r], e2c);
                    if (s < bs[m][r]) { bs[m][r] = s; bi[m][r] = c_lane; }
                }
            }
        }
        if (kc < 15) {
            _Float16* w1 = ep + nxt * 2 * EP_PLANE;
            _Float16* w2 = w1 + EP_PLANE;
            #pragma unroll
            for (int pass = 0; pass < 4; ++pass) {
                const int c_loc = (tid >> 4) + pass * 16;
                const int j4    = (tid & 15) * 4;
                const float4 v = ev[pass];
                f16x4 h1, h2;
                h1[0] = (_Float16)v.x; h2[0] = (_Float16)(v.x - (float)h1[0]);
                h1[1] = (_Float16)v.y; h2[1] = (_Float16)(v.y - (float)h1[1]);
                h1[2] = (_Float16)v.z; h2[2] = (_Float16)(v.z - (float)h1[2]);
                h1[3] = (_Float16)v.w; h2[3] = (_Float16)(v.w - (float)h1[3]);
                *(f16x4*)(w1 + c_loc * EP_ROW + j4) = h1;
                *(f16x4*)(w2 + c_loc * EP_ROW + j4) = h2;
            }
        }
        __syncthreads();
    }
    float mdloc = 0.f;
    #pragma unroll
    for (int m = 0; m < 2; ++m)
        #pragma unroll
        for (int r = 0; r < 4; ++r) {
            float s = bs[m][r]; int i = bi[m][r];
            #pragma unroll
            for (int mask = 1; mask < 16; mask <<= 1) {
                const float s2 = __shfl_xor(s, mask);
                const int   i2 = __shfl_xor(i, mask);
                if (s2 < s || (s2 == s && i2 < i)) { s = s2; i = i2; }
            }
            if (ln == 0) {
                const int t_loc = w * 32 + m * 16 + q * 4 + r;
                ibest[t_loc] = i;
                out_idx[b * TT + t0 + t_loc] = (float)i;
                atomicAdd(&counts[i], 1.0f);
                mdloc += x2s[t_loc] + s;
            }
        }
    if (ln == 0) atomicAdd(mdsum, mdloc);
    __syncthreads();
    if (tid == 0) atomicAdd(distsum, mdsum[0]);
    #pragma unroll
    for (int p = 0; p < 32; ++p) {
        const int f  = p * 256 + tid;
        const int j  = f >> 7;
        const int tt = f & 127;
        out_q[(size_t)(b * DIM + j) * TT + t0 + tt] =
            embed[(size_t)ibest[tt] * DIM + j];
    }
}

// finalize: in-place counts->avg_probs, perplexity, usage, commitment
__global__ __launch_bounds__(1024) void finalize_kernel(
    float* __restrict__ avg, float* __restrict__ commit_slot,
    float* __restrict__ out_perp, float* __restrict__ out_usage)
{
    __shared__ float s_ent[1024];
    __shared__ float s_use[1024];
    const int k = threadIdx.x;
    const float p = avg[k] * (1.0f / (float)NTOT);
    avg[k] = p;
    s_ent[k] = p * logf(p + 1e-10f);
    s_use[k] = p * logf(p * 1024.f + 1e-10f);
    __syncthreads();
    for (int off = 512; off > 0; off >>= 1) {
        if (k < off) { s_ent[k] += s_ent[k + off]; s_use[k] += s_use[k + off]; }
        __syncthreads();
    }
    if (k == 0) {
        const float ds = commit_slot[0];
        *out_perp      = expf(-s_ent[0]);
        *out_usage     = s_use[0];
        commit_slot[0] = 0.25f * ds * (1.0f / ((float)NTOT * (float)DIM));
    }
}

extern "C" void kernel_launch(void* const* d_in, const int* in_sizes, int n_in,
                              void* d_out, int out_size, void* d_ws, size_t ws_size,
                              hipStream_t stream) {
    const float* x     = (const float*)d_in[0];
    const float* embed = (const float*)d_in[1];

    float* out        = (float*)d_out;
    float* out_q      = out;             // 4194304
    float* out_commit = out + 4194304;   // distsum accumulator first
    float* out_perp   = out + 4194305;
    float* out_avg    = out + 4194306;   // counts accumulator first
    float* out_idx    = out + 4195330;
    // usage at out + 4260866

    if (ws_size >= WS_NEED) {
        _Float16* planes = (_Float16*)d_ws;
        float*    e2g    = (float*)((char*)d_ws + 262144);
        prep_kernel<<<32, 256, 0, stream>>>(embed, planes, e2g, out_avg, out_commit);
        argmin_fused<<<512, 512, 0, stream>>>(x, (const f16x8*)planes, e2g, embed,
                                              out_q, out_idx, out_avg, out_commit);
    } else {
        hipMemsetAsync(out_commit, 0, 1026 * sizeof(float), stream);
        argmin_fb<<<512, 256, 0, stream>>>(x, embed, out_q, out_idx, out_avg, out_commit);
    }
    finalize_kernel<<<1, 1024, 0, stream>>>(out_avg, out_commit, out_perp, out + 4260866);
}